// Round 9
// baseline (194.356 us; speedup 1.0000x reference)
//
#include <hip/hip_runtime.h>
#include <hip/hip_bf16.h>

typedef _Float16 f16;
typedef __attribute__((ext_vector_type(2))) _Float16 f16x2;
typedef __attribute__((ext_vector_type(8))) _Float16 f16x8;
typedef __attribute__((ext_vector_type(16))) float f32x16;

#define BNSCL 0.9999950000375f   /* 1/sqrt(1+1e-5) */

// ---------------------------------------------------------------------------
// Kernel 1: per-point scores MLP + softmax, 2 pts/thread. ROUND 9: MLP
// weights/gains read DIRECT from global with constant indices -> compiler
// emits scalar s_load (K$), eliminating ~752 broadcast ds_read_b32/thread
// (the old lw staging made k_scores LDS-unit-bound, ~15 us). LDS deleted.
// Fused: blocks < 256 build wbtA (r8 layout, both banks):
//   wbtA[((ot*64 + bank*32 + ks)*64 + lane)*8 + j], c = ks*2+(lane>>5),
//   o = ot*32+(lane&31); bank0 S = wbD+wbR, bank1 D = wbD.
// ---------------------------------------------------------------------------
__global__ __launch_bounds__(256) void k_scores(
    const float* __restrict__ xyz,
    const float* __restrict__ w1, const float* __restrict__ g1, const float* __restrict__ be1,
    const float* __restrict__ w2, const float* __restrict__ g2, const float* __restrict__ be2,
    const float* __restrict__ w3, const float* __restrict__ g3, const float* __restrict__ be3,
    const float* __restrict__ w4, const float* __restrict__ b4,
    const float* __restrict__ wb, f16* __restrict__ wbtA,
    f16* __restrict__ scores)
{
    const int tid = threadIdx.x;

    // fused weight-bank fragment-order transpose (1 elem/thread, blocks 0-255)
    if (blockIdx.x < 256) {
        int idx = blockIdx.x * 256 + tid;       // 0..65535
        int j    = idx & 7;
        int lane = (idx >> 3) & 63;
        int ks   = (idx >> 9) & 31;
        int bank = (idx >> 14) & 1;             // 0 = S (combined), 1 = D
        int ot   = idx >> 15;
        int c    = ks * 2 + (lane >> 5);        // 0..63
        int o    = ot * 32 + (lane & 31);
        float vD = wb[(c * 8 + j) * 64 + o];
        float v  = bank ? vD : vD + wb[((c + 64) * 8 + j) * 64 + o];
        wbtA[idx] = (f16)v;
    }

    float in7[2][7], h1[2][16], h2[2][16], s[2][8];

#pragma unroll
    for (int q = 0; q < 2; ++q) {
        int g = blockIdx.x * 512 + q * 256 + tid;
        int b = g >> 15;
        int p = g & 32767;
        int pc = p & ~31;
        const float* xb = xyz + (size_t)b * 98304;
        float cx = xb[pc], cy = xb[32768 + pc], cz = xb[65536 + pc];
        float dx = xb[p] - cx, dy = xb[32768 + p] - cy, dz = xb[65536 + p] - cz;
        in7[q][0] = cx; in7[q][1] = cy; in7[q][2] = cz;
        in7[q][3] = dx; in7[q][4] = dy; in7[q][5] = dz;
        in7[q][6] = sqrtf(dx * dx + dy * dy + dz * dz);
    }

#pragma unroll
    for (int o = 0; o < 16; ++o) {
        float a0 = 0.f, a1 = 0.f;
#pragma unroll
        for (int c = 0; c < 7; ++c) {
            float w = w1[o * 7 + c];
            a0 += w * in7[0][c]; a1 += w * in7[1][c];
        }
        float gs = g1[o] * BNSCL, bb = be1[o];
        h1[0][o] = fmaxf(a0 * gs + bb, 0.f);
        h1[1][o] = fmaxf(a1 * gs + bb, 0.f);
    }
#pragma unroll
    for (int o = 0; o < 16; ++o) {
        float a0 = 0.f, a1 = 0.f;
#pragma unroll
        for (int c = 0; c < 16; ++c) {
            float w = w2[o * 16 + c];
            a0 += w * h1[0][c]; a1 += w * h1[1][c];
        }
        float gs = g2[o] * BNSCL, bb = be2[o];
        h2[0][o] = fmaxf(a0 * gs + bb, 0.f);
        h2[1][o] = fmaxf(a1 * gs + bb, 0.f);
    }
#pragma unroll
    for (int o = 0; o < 16; ++o) {
        float a0 = 0.f, a1 = 0.f;
#pragma unroll
        for (int c = 0; c < 16; ++c) {
            float w = w3[o * 16 + c];
            a0 += w * h2[0][c]; a1 += w * h2[1][c];
        }
        float gs = g3[o] * BNSCL, bb = be3[o];
        h1[0][o] = fmaxf(a0 * gs + bb, 0.f);
        h1[1][o] = fmaxf(a1 * gs + bb, 0.f);
    }
#pragma unroll
    for (int o = 0; o < 8; ++o) {
        float bb = b4[o];
        float a0 = bb, a1 = bb;
#pragma unroll
        for (int c = 0; c < 16; ++c) {
            float w = w4[o * 16 + c];
            a0 += w * h1[0][c]; a1 += w * h1[1][c];
        }
        s[0][o] = a0; s[1][o] = a1;
    }

#pragma unroll
    for (int q = 0; q < 2; ++q) {
        int g = blockIdx.x * 512 + q * 256 + tid;
        float mx = s[q][0];
#pragma unroll
        for (int i = 1; i < 8; ++i) mx = fmaxf(mx, s[q][i]);
        float sum = 0.f;
#pragma unroll
        for (int i = 0; i < 8; ++i) { s[q][i] = __expf(s[q][i] - mx); sum += s[q][i]; }
        float inv = 1.f / sum;
        f16x8 o8;
#pragma unroll
        for (int i = 0; i < 8; ++i) o8[i] = (f16)(s[q][i] * inv);
        *(f16x8*)(scores + (size_t)g * 8) = o8;
    }
}

// ---------------------------------------------------------------------------
// Kernel 2 (NEW, round 9): k_g — externalized center-term G.
// G depends only on the GROUP center: Gt[g][o][m] = -sum_c fc[c,g]*wbD[c,m,o].
// This is r8's in-loop accG machinery verbatim (D-bank A-fragments, diagonal
// mask B, C/D->[g][o][m] bounce), moved out of the per-point hot loop so
// k_main sheds 1 b128 + 2 b32 LDS reads + 1 MFMA + ~12 VALU per KSTEP.
// Block = 1024 thr / 16 waves; wave = one 64-pt window (2 groups), ot fixed
// per block (bx>>8). fc read direct from global (2 broadcast loads/kk).
// Output written coalesced (16 B/lane) via per-wave LDS bounce.
// ---------------------------------------------------------------------------
__global__ __launch_bounds__(1024) void k_g(
    const float* __restrict__ feat,
    const f16* __restrict__ wbtA,
    f16* __restrict__ Gt)
{
    __shared__ __align__(16) f16 ldsD[16384];    // 32 KB D-bank (this ot)
    __shared__ __align__(16) f16 gscr[16][512];  // 16 KB bounce

    const int tid  = threadIdx.x;
    const int lane = tid & 63;
    const int wave = tid >> 6;              // 0..15
    const int l31  = lane & 31;
    const int lh   = lane >> 5;             // 0..1

    const int ot     = blockIdx.x >> 8;             // 0..1
    const int window = (blockIdx.x & 255) * 16 + wave;   // 0..4095
    const int ptglob = window * 64;
    const int b      = ptglob >> 15;
    const int ptb    = ptglob & 32767;
    const float* fb  = feat + (size_t)b * 2097152;

    // stage D bank (second 16384 f16 of this ot's wbtA block)
    const f16* src = wbtA + ot * 32768 + 16384;
#pragma unroll
    for (int it = 0; it < 2; ++it) {
        int idx = it * 1024 + tid;                   // 0..2047 16B-chunks
        *(int4*)&ldsD[idx << 3] = *(const int4*)&src[idx << 3];
    }
    __syncthreads();

    // diagonal-mask pairs (r8-proven): col l31<16 contributes slot m=l31&7
    // for group g=l31>>3; other cols zero.
    const bool mon  = (l31 < 16);
    const int  mpos = l31 & 7;
    const f16x2 mk0 = { (f16)((mon && mpos == 0) ? 1.f : 0.f),
                        (f16)((mon && mpos == 1) ? 1.f : 0.f) };
    const f16x2 mk1 = { (f16)((mon && mpos == 2) ? 1.f : 0.f),
                        (f16)((mon && mpos == 3) ? 1.f : 0.f) };
    const f16x2 mk2 = { (f16)((mon && mpos == 4) ? 1.f : 0.f),
                        (f16)((mon && mpos == 5) ? 1.f : 0.f) };
    const f16x2 mk3 = { (f16)((mon && mpos == 6) ? 1.f : 0.f),
                        (f16)((mon && mpos == 7) ? 1.f : 0.f) };

    f32x16 accG = {};
    const f16* Ad = ldsD + (lane << 3);

#pragma unroll
    for (int kk = 0; kk < 32; ++kk) {
        f16x8 aD = *(const f16x8*)(Ad + ((size_t)kk << 9));
        const float* frow = fb + ((size_t)(2 * kk + lh) << 15) + ptb;
        float fcs = (l31 & 8) ? frow[32] : frow[0];
        f16 hC = (f16)(-fcs);
        f16x2 fg2 = {hC, hC};
        f16x2 q0 = mk0 * fg2, q1 = mk1 * fg2, q2 = mk2 * fg2, q3 = mk3 * fg2;
        f16x8 bG = {q0[0],q0[1],q1[0],q1[1],q2[0],q2[1],q3[0],q3[1]};
        accG = __builtin_amdgcn_mfma_f32_32x32x16_f16(aD, bG, accG, 0, 0, 0);
    }

    // bounce accG (C/D layout: col=g*8+m for col<16; row o) -> [g][o][m]
    if (l31 < 16) {
        const int base = (l31 >> 3) * 256 + (l31 & 7);   // g*256 + m
#pragma unroll
        for (int r = 0; r < 16; ++r) {
            int o = (r & 3) + ((r >> 2) << 3) + (lh << 2);
            gscr[wave][base + o * 8] = (f16)accG[r];
        }
    }
    asm volatile("s_waitcnt lgkmcnt(0)" ::: "memory");
    __builtin_amdgcn_sched_barrier(0);
    {
        // lane (l31,lh) carries Gt[window*2+lh][ot*32+l31][m 0..7] (16 B)
        f16x8 gv = *(const f16x8*)&gscr[wave][lh * 256 + l31 * 8];
        size_t gg = (size_t)(window * 2 + lh);
        *(f16x8*)&Gt[(gg * 64 + ot * 32 + l31) * 8] = gv;
    }
}

// ---------------------------------------------------------------------------
// Kernel 3: main einsum, 32x32x16 f16 MFMA.
// ROUND 9: G externalized (see k_g). KSTEP is now 1 ds_read_b128 (S bank) +
// 2 ds_read_b32 (fv only; fc gone) + 8 f16x2 muls + 2 MFMA — per-CU LDS
// demand ~halved vs r8 (the measured wall tracked LDS+VALU+MFMA demand).
// Weights LDS 64->32 KB (S only); gscr/masks/accG deleted. Epilogue applies
// the center correction with 2 MFMAs (r8-proven structure) whose A-fragment
// is a coalesced 16 B/lane load from Gt. Schedule = r6 distance-6 DMA
// pipeline unchanged (WAITV(12), barrier-free feat staging).
// ---------------------------------------------------------------------------
__global__ __launch_bounds__(1024, 4) void k_main(
    const float* __restrict__ feat,
    const f16* __restrict__ scores,
    const f16* __restrict__ wbtA,
    const f16* __restrict__ Gt,
    const float* __restrict__ bn_g, const float* __restrict__ bn_b,
    float* __restrict__ out)
{
    __shared__ __align__(16) f16 lwb[16384];         // 32 KB S-bank weights
    __shared__ __align__(16) float fbuf[8][2][1024]; // 64 KB feat 8-slot buf

    const int tid  = threadIdx.x;
    const int lane = tid & 63;
    const int wave = tid >> 6;          // 0..15
    const int l31  = lane & 31;
    const int lh   = lane >> 5;         // 0..1
    const int w64  = wave * 64;

    const int ot = blockIdx.x >> 8;             // 0..1 (o-tile half)
    const int g  = blockIdx.x & 255;            // point-group
    const int pblock = g * 1024;                // global point base
    const int b    = pblock >> 15;
    const int pt0  = (pblock & 32767) + w64;    // within-batch, 32-aligned
    const int pc0  = pt0 + l31;
    const int pc1  = pc0 + 32;

    const float* fb = feat + (size_t)b * 2097152;    // (64, 32768)
    const float* gsrc0 = fb + (pblock & 32767) + w64 + lane;

    // ---- stage this ot's 32 KB S-bank into LDS ----
    const f16* src = wbtA + ot * 32768;              // S bank first
#pragma unroll
    for (int it = 0; it < 2; ++it) {
        int idx = it * 1024 + tid;                   // 0..2047 16B-chunks
        *(int4*)&lwb[idx << 3] = *(const int4*)&src[idx << 3];
    }

    // ---- scores: load + extract to registers ----
    const int gpt = pblock + w64 + l31;
    f16x8 sv0 = *(const f16x8*)(scores + (size_t)gpt * 8);
    f16x8 sv1 = *(const f16x8*)(scores + (size_t)(gpt + 32) * 8);
    const f16x2 s0a = {sv0[0], sv0[1]}, s0b = {sv0[2], sv0[3]},
                s0c = {sv0[4], sv0[5]}, s0d = {sv0[6], sv0[7]};
    const f16x2 s1a = {sv1[0], sv1[1]}, s1b = {sv1[2], sv1[3]},
                s1c = {sv1[4], sv1[5]}, s1d = {sv1[6], sv1[7]};

    f32x16 acc0 = {}, acc1 = {};
    const f16* Alds = lwb + (lane << 3);             // lane's 16B slot

#define STAGE(t)                                                               \
    {                                                                          \
        __builtin_amdgcn_global_load_lds(                                      \
            (const __attribute__((address_space(1))) void*)                    \
                (gsrc0 + ((size_t)(2 * (t)) << 15)),                           \
            (__attribute__((address_space(3))) void*)&fbuf[(t) & 7][0][w64],   \
            4, 0, 0);                                                          \
        __builtin_amdgcn_global_load_lds(                                      \
            (const __attribute__((address_space(1))) void*)                    \
                (gsrc0 + ((size_t)(2 * (t) + 1) << 15)),                       \
            (__attribute__((address_space(3))) void*)&fbuf[(t) & 7][1][w64],   \
            4, 0, 0);                                                          \
    }

#define WAITV(n) asm volatile("s_waitcnt vmcnt(" #n ")" ::: "memory")

    __builtin_amdgcn_sched_barrier(0);
    STAGE(0); STAGE(1); STAGE(2); STAGE(3); STAGE(4); STAGE(5);

    asm volatile("s_waitcnt lgkmcnt(0)" ::: "memory");
    __builtin_amdgcn_s_barrier();

#define KSTEP(kk)                                                              \
    {                                                                          \
        f16x8 aS = *(const f16x8*)(Alds + ((size_t)(kk) << 9));                \
        const float* frow = fbuf[(kk) & 7][lh];                                \
        float fv0 = frow[w64 + l31], fv1 = frow[w64 + l31 + 32];               \
        f16 hR0 = (f16)fv0, hR1 = (f16)fv1;                                    \
        f16x2 fR0 = {hR0, hR0}, fR1 = {hR1, hR1};                              \
        f16x2 r0a = fR0 * s0a, r0b = fR0 * s0b, r0c = fR0 * s0c, r0d = fR0 * s0d; \
        f16x2 r1a = fR1 * s1a, r1b = fR1 * s1b, r1c = fR1 * s1c, r1d = fR1 * s1d; \
        f16x8 bS0 = {r0a[0],r0a[1],r0b[0],r0b[1],r0c[0],r0c[1],r0d[0],r0d[1]}; \
        f16x8 bS1 = {r1a[0],r1a[1],r1b[0],r1b[1],r1c[0],r1c[1],r1d[0],r1d[1]}; \
        acc0 = __builtin_amdgcn_mfma_f32_32x32x16_f16(aS, bS0, acc0, 0, 0, 0); \
        acc1 = __builtin_amdgcn_mfma_f32_32x32x16_f16(aS, bS1, acc1, 0, 0, 0); \
    }

#define PAIR(p)                                                                \
    STAGE(2 * (p) + 6) STAGE(2 * (p) + 7)                                      \
    WAITV(12);                                                                 \
    KSTEP(2 * (p)) KSTEP(2 * (p) + 1)

    PAIR(0)  PAIR(1)  PAIR(2)  PAIR(3)
    PAIR(4)  PAIR(5)  PAIR(6)  PAIR(7)
    PAIR(8)  PAIR(9)  PAIR(10) PAIR(11)
    PAIR(12)
    WAITV(8);
    KSTEP(26) KSTEP(27)
    WAITV(4);
    KSTEP(28) KSTEP(29)
    WAITV(0);
    KSTEP(30) KSTEP(31)
#undef PAIR
#undef KSTEP
#undef STAGE
#undef WAITV

    __builtin_amdgcn_sched_barrier(0);

    // ---- center correction: A = (-G) fragment from Gt (16 B/lane), B =
    // resident score regs half-zeroed; k-slot (lh*8+j) <-> (group lh, m=j).
    {
        const int g0 = (pblock + w64) >> 5;          // wave's first group
        const f16x8 a2 = *(const f16x8*)
            &Gt[((size_t)(g0 + lh) * 64 + ot * 32 + l31) * 8];
        f16x8 z8 = {};
        f16x8 bC0 = lh ? z8 : sv0;
        f16x8 bC1 = lh ? sv1 : z8;
        acc0 = __builtin_amdgcn_mfma_f32_32x32x16_f16(a2, bC0, acc0, 0, 0, 0);
        acc1 = __builtin_amdgcn_mfma_f32_32x32x16_f16(a2, bC1, acc1, 0, 0, 0);
    }

    // ---------------- epilogue: BN + ReLU + coalesced store ------------------
#pragma unroll
    for (int r = 0; r < 16; ++r) {
        int o = ot * 32 + (r & 3) + ((r >> 2) << 3) + (lh << 2);
        float gs = bn_g[o] * BNSCL, bb = bn_b[o];
        size_t row = (size_t)(b * 64 + o) << 15;
        out[row + pc0] = fmaxf(acc0[r] * gs + bb, 0.f);
        out[row + pc1] = fmaxf(acc1[r] * gs + bb, 0.f);
    }
}

// ---------------------------------------------------------------------------
extern "C" void kernel_launch(void* const* d_in, const int* in_sizes, int n_in,
                              void* d_out, int out_size, void* d_ws, size_t ws_size,
                              hipStream_t stream)
{
    const float* features = (const float*)d_in[0];
    const float* xyz      = (const float*)d_in[1];
    const float* w1  = (const float*)d_in[2];
    const float* g1  = (const float*)d_in[3];
    const float* be1 = (const float*)d_in[4];
    const float* w2  = (const float*)d_in[5];
    const float* g2  = (const float*)d_in[6];
    const float* be2 = (const float*)d_in[7];
    const float* w3  = (const float*)d_in[8];
    const float* g3  = (const float*)d_in[9];
    const float* be3 = (const float*)d_in[10];
    const float* w4  = (const float*)d_in[11];
    const float* b4  = (const float*)d_in[12];
    const float* wb  = (const float*)d_in[13];
    const float* bn_g = (const float*)d_in[14];
    const float* bn_b = (const float*)d_in[15];

    f16* scores = (f16*)d_ws;                                   // 4 MB
    f16* wbtA   = (f16*)((char*)d_ws + (4u << 20));             // 128 KB
    f16* Gt     = (f16*)((char*)d_ws + (4u << 20) + 131072);    // 8 MB

    k_scores<<<512, 256, 0, stream>>>(xyz, w1, g1, be1, w2, g2, be2,
                                      w3, g3, be3, w4, b4, wb, wbtA, scores);
    k_g<<<512, 1024, 0, stream>>>(features, wbtA, Gt);
    k_main<<<512, 1024, 0, stream>>>(features, scores, wbtA, Gt,
                                     bn_g, bn_b, (float*)d_out);
}

// Round 10
// 188.610 us; speedup vs baseline: 1.0305x; 1.0305x over previous
//
#include <hip/hip_runtime.h>
#include <hip/hip_bf16.h>

typedef _Float16 f16;
typedef __attribute__((ext_vector_type(2))) _Float16 f16x2;
typedef __attribute__((ext_vector_type(8))) _Float16 f16x8;
typedef __attribute__((ext_vector_type(16))) float f32x16;

#define BNSCL 0.9999950000375f   /* 1/sqrt(1+1e-5) */

// ---------------------------------------------------------------------------
// Kernel 1 (ROUND 10): k_pre — fused pre-pass, 512-thr blocks, grid 1280.
//   blocks 0..255   : scores MLP + softmax (2 pts/thread; weights read direct
//                     from global, scalar K$ loads — r9-verified).
//                     blocks 0..127 also build wbtA (r8 layout, both banks).
//   blocks 256..1279: G-GEMM (r9 k_g verbatim per-wave job, 8 waves/block).
//                     D-bank gathered DIRECT from wb (not wbtA!) so there is
//                     no intra-grid dependency; Gt[g][o][m] written coalesced.
// Rationale: r9 proved the G externalization (k_main 49.8 -> 40.8) but its
// separate launch cost +32 us total. Same work, zero extra launches.
// ---------------------------------------------------------------------------
__global__ __launch_bounds__(512) void k_pre(
    const float* __restrict__ xyz,
    const float* __restrict__ w1, const float* __restrict__ g1, const float* __restrict__ be1,
    const float* __restrict__ w2, const float* __restrict__ g2, const float* __restrict__ be2,
    const float* __restrict__ w3, const float* __restrict__ g3, const float* __restrict__ be3,
    const float* __restrict__ w4, const float* __restrict__ b4,
    const float* __restrict__ wb, f16* __restrict__ wbtA,
    const float* __restrict__ feat, f16* __restrict__ Gt,
    f16* __restrict__ scores)
{
    __shared__ __align__(16) f16 ldsD[16384];   // 32 KB D-bank (G blocks only)
    __shared__ __align__(16) f16 gscr[8][512];  // 8 KB bounce (G blocks only)

    const int tid = threadIdx.x;
    const int bx  = blockIdx.x;

    if (bx >= 256) {
        // =================== G blocks ===================
        const int gb   = bx - 256;              // 0..1023
        const int ot   = gb >> 9;               // 0..1 (uniform per block)
        const int lane = tid & 63;
        const int wave = tid >> 6;              // 0..7
        const int l31  = lane & 31;
        const int lh   = lane >> 5;             // 0..1

        // ---- gather D bank from wb directly into wbtA-bank1 layout ----
        // ldsD[(ks*64+lane)*8+j] = (f16)wb[(c*8+j)*64+o], c=ks*2+(lane>>5),
        // o=ot*32+(lane&31).
#pragma unroll
        for (int it = 0; it < 4; ++it) {
            int oct = it * 512 + tid;           // 0..2047 (octet index)
            int ln  = oct & 63;
            int ks  = oct >> 6;                 // 0..31
            int c   = ks * 2 + (ln >> 5);
            int o   = ot * 32 + (ln & 31);
            f16x8 v;
#pragma unroll
            for (int j = 0; j < 8; ++j) v[j] = (f16)wb[(c * 8 + j) * 64 + o];
            *(f16x8*)&ldsD[oct << 3] = v;
        }
        __syncthreads();

        const int window = (gb & 511) * 8 + wave;    // 0..4095
        const int ptglob = window * 64;
        const int b      = ptglob >> 15;
        const int ptb    = ptglob & 32767;
        const float* fb  = feat + (size_t)b * 2097152;

        // diagonal-mask pairs (r8/r9-proven)
        const bool mon  = (l31 < 16);
        const int  mpos = l31 & 7;
        const f16x2 mk0 = { (f16)((mon && mpos == 0) ? 1.f : 0.f),
                            (f16)((mon && mpos == 1) ? 1.f : 0.f) };
        const f16x2 mk1 = { (f16)((mon && mpos == 2) ? 1.f : 0.f),
                            (f16)((mon && mpos == 3) ? 1.f : 0.f) };
        const f16x2 mk2 = { (f16)((mon && mpos == 4) ? 1.f : 0.f),
                            (f16)((mon && mpos == 5) ? 1.f : 0.f) };
        const f16x2 mk3 = { (f16)((mon && mpos == 6) ? 1.f : 0.f),
                            (f16)((mon && mpos == 7) ? 1.f : 0.f) };

        f32x16 accG = {};
        const f16* Ad = ldsD + (lane << 3);

#pragma unroll
        for (int kk = 0; kk < 32; ++kk) {
            f16x8 aD = *(const f16x8*)(Ad + ((size_t)kk << 9));
            const float* frow = fb + ((size_t)(2 * kk + lh) << 15) + ptb;
            float fcs = (l31 & 8) ? frow[32] : frow[0];
            f16 hC = (f16)(-fcs);
            f16x2 fg2 = {hC, hC};
            f16x2 q0 = mk0 * fg2, q1 = mk1 * fg2, q2 = mk2 * fg2, q3 = mk3 * fg2;
            f16x8 bG = {q0[0],q0[1],q1[0],q1[1],q2[0],q2[1],q3[0],q3[1]};
            accG = __builtin_amdgcn_mfma_f32_32x32x16_f16(aD, bG, accG, 0, 0, 0);
        }

        // bounce accG (C/D: col=g*8+m for col<16; row o) -> [g][o][m]
        if (l31 < 16) {
            const int base = (l31 >> 3) * 256 + (l31 & 7);   // g*256 + m
#pragma unroll
            for (int r = 0; r < 16; ++r) {
                int o = (r & 3) + ((r >> 2) << 3) + (lh << 2);
                gscr[wave][base + o * 8] = (f16)accG[r];
            }
        }
        asm volatile("s_waitcnt lgkmcnt(0)" ::: "memory");
        __builtin_amdgcn_sched_barrier(0);
        {
            f16x8 gv = *(const f16x8*)&gscr[wave][lh * 256 + l31 * 8];
            size_t gg = (size_t)(window * 2 + lh);
            *(f16x8*)&Gt[(gg * 64 + ot * 32 + l31) * 8] = gv;
        }
        return;
    }

    // =================== MLP / softmax blocks (0..255) ===================
    // fused weight-bank fragment-order transpose (blocks 0..127, 1 elem/thr/512)
    if (bx < 128) {
        int idx = bx * 512 + tid;               // 0..65535
        int j    = idx & 7;
        int lane = (idx >> 3) & 63;
        int ks   = (idx >> 9) & 31;
        int bank = (idx >> 14) & 1;             // 0 = S (combined), 1 = D
        int ot   = idx >> 15;
        int c    = ks * 2 + (lane >> 5);        // 0..63
        int o    = ot * 32 + (lane & 31);
        float vD = wb[(c * 8 + j) * 64 + o];
        float v  = bank ? vD : vD + wb[((c + 64) * 8 + j) * 64 + o];
        wbtA[idx] = (f16)v;
    }

    float in7[2][7], h1[2][16], h2[2][16], s[2][8];

#pragma unroll
    for (int q = 0; q < 2; ++q) {
        int g = bx * 1024 + q * 512 + tid;
        int b = g >> 15;
        int p = g & 32767;
        int pc = p & ~31;
        const float* xb = xyz + (size_t)b * 98304;
        float cx = xb[pc], cy = xb[32768 + pc], cz = xb[65536 + pc];
        float dx = xb[p] - cx, dy = xb[32768 + p] - cy, dz = xb[65536 + p] - cz;
        in7[q][0] = cx; in7[q][1] = cy; in7[q][2] = cz;
        in7[q][3] = dx; in7[q][4] = dy; in7[q][5] = dz;
        in7[q][6] = sqrtf(dx * dx + dy * dy + dz * dz);
    }

#pragma unroll
    for (int o = 0; o < 16; ++o) {
        float a0 = 0.f, a1 = 0.f;
#pragma unroll
        for (int c = 0; c < 7; ++c) {
            float w = w1[o * 7 + c];
            a0 += w * in7[0][c]; a1 += w * in7[1][c];
        }
        float gs = g1[o] * BNSCL, bb = be1[o];
        h1[0][o] = fmaxf(a0 * gs + bb, 0.f);
        h1[1][o] = fmaxf(a1 * gs + bb, 0.f);
    }
#pragma unroll
    for (int o = 0; o < 16; ++o) {
        float a0 = 0.f, a1 = 0.f;
#pragma unroll
        for (int c = 0; c < 16; ++c) {
            float w = w2[o * 16 + c];
            a0 += w * h1[0][c]; a1 += w * h1[1][c];
        }
        float gs = g2[o] * BNSCL, bb = be2[o];
        h2[0][o] = fmaxf(a0 * gs + bb, 0.f);
        h2[1][o] = fmaxf(a1 * gs + bb, 0.f);
    }
#pragma unroll
    for (int o = 0; o < 16; ++o) {
        float a0 = 0.f, a1 = 0.f;
#pragma unroll
        for (int c = 0; c < 16; ++c) {
            float w = w3[o * 16 + c];
            a0 += w * h2[0][c]; a1 += w * h2[1][c];
        }
        float gs = g3[o] * BNSCL, bb = be3[o];
        h1[0][o] = fmaxf(a0 * gs + bb, 0.f);
        h1[1][o] = fmaxf(a1 * gs + bb, 0.f);
    }
#pragma unroll
    for (int o = 0; o < 8; ++o) {
        float bb = b4[o];
        float a0 = bb, a1 = bb;
#pragma unroll
        for (int c = 0; c < 16; ++c) {
            float w = w4[o * 16 + c];
            a0 += w * h1[0][c]; a1 += w * h1[1][c];
        }
        s[0][o] = a0; s[1][o] = a1;
    }

#pragma unroll
    for (int q = 0; q < 2; ++q) {
        int g = bx * 1024 + q * 512 + tid;
        float mx = s[q][0];
#pragma unroll
        for (int i = 1; i < 8; ++i) mx = fmaxf(mx, s[q][i]);
        float sum = 0.f;
#pragma unroll
        for (int i = 0; i < 8; ++i) { s[q][i] = __expf(s[q][i] - mx); sum += s[q][i]; }
        float inv = 1.f / sum;
        f16x8 o8;
#pragma unroll
        for (int i = 0; i < 8; ++i) o8[i] = (f16)(s[q][i] * inv);
        *(f16x8*)(scores + (size_t)g * 8) = o8;
    }
}

// ---------------------------------------------------------------------------
// Kernel 2: main einsum — BYTE-IDENTICAL to round 9 (verified, 40.8 us).
// 1 ds_read_b128 + 2 ds_read_b32 + 8 muls + 2 MFMA per KSTEP; r6 distance-6
// DMA pipeline; epilogue center-correction via 2 MFMAs with A from Gt.
// ---------------------------------------------------------------------------
__global__ __launch_bounds__(1024, 4) void k_main(
    const float* __restrict__ feat,
    const f16* __restrict__ scores,
    const f16* __restrict__ wbtA,
    const f16* __restrict__ Gt,
    const float* __restrict__ bn_g, const float* __restrict__ bn_b,
    float* __restrict__ out)
{
    __shared__ __align__(16) f16 lwb[16384];         // 32 KB S-bank weights
    __shared__ __align__(16) float fbuf[8][2][1024]; // 64 KB feat 8-slot buf

    const int tid  = threadIdx.x;
    const int lane = tid & 63;
    const int wave = tid >> 6;          // 0..15
    const int l31  = lane & 31;
    const int lh   = lane >> 5;         // 0..1
    const int w64  = wave * 64;

    const int ot = blockIdx.x >> 8;             // 0..1 (o-tile half)
    const int g  = blockIdx.x & 255;            // point-group
    const int pblock = g * 1024;                // global point base
    const int b    = pblock >> 15;
    const int pt0  = (pblock & 32767) + w64;    // within-batch, 32-aligned
    const int pc0  = pt0 + l31;
    const int pc1  = pc0 + 32;

    const float* fb = feat + (size_t)b * 2097152;    // (64, 32768)
    const float* gsrc0 = fb + (pblock & 32767) + w64 + lane;

    // ---- stage this ot's 32 KB S-bank into LDS ----
    const f16* src = wbtA + ot * 32768;              // S bank first
#pragma unroll
    for (int it = 0; it < 2; ++it) {
        int idx = it * 1024 + tid;                   // 0..2047 16B-chunks
        *(int4*)&lwb[idx << 3] = *(const int4*)&src[idx << 3];
    }

    // ---- scores: load + extract to registers ----
    const int gpt = pblock + w64 + l31;
    f16x8 sv0 = *(const f16x8*)(scores + (size_t)gpt * 8);
    f16x8 sv1 = *(const f16x8*)(scores + (size_t)(gpt + 32) * 8);
    const f16x2 s0a = {sv0[0], sv0[1]}, s0b = {sv0[2], sv0[3]},
                s0c = {sv0[4], sv0[5]}, s0d = {sv0[6], sv0[7]};
    const f16x2 s1a = {sv1[0], sv1[1]}, s1b = {sv1[2], sv1[3]},
                s1c = {sv1[4], sv1[5]}, s1d = {sv1[6], sv1[7]};

    f32x16 acc0 = {}, acc1 = {};
    const f16* Alds = lwb + (lane << 3);             // lane's 16B slot

#define STAGE(t)                                                               \
    {                                                                          \
        __builtin_amdgcn_global_load_lds(                                      \
            (const __attribute__((address_space(1))) void*)                    \
                (gsrc0 + ((size_t)(2 * (t)) << 15)),                           \
            (__attribute__((address_space(3))) void*)&fbuf[(t) & 7][0][w64],   \
            4, 0, 0);                                                          \
        __builtin_amdgcn_global_load_lds(                                      \
            (const __attribute__((address_space(1))) void*)                    \
                (gsrc0 + ((size_t)(2 * (t) + 1) << 15)),                       \
            (__attribute__((address_space(3))) void*)&fbuf[(t) & 7][1][w64],   \
            4, 0, 0);                                                          \
    }

#define WAITV(n) asm volatile("s_waitcnt vmcnt(" #n ")" ::: "memory")

    __builtin_amdgcn_sched_barrier(0);
    STAGE(0); STAGE(1); STAGE(2); STAGE(3); STAGE(4); STAGE(5);

    asm volatile("s_waitcnt lgkmcnt(0)" ::: "memory");
    __builtin_amdgcn_s_barrier();

#define KSTEP(kk)                                                              \
    {                                                                          \
        f16x8 aS = *(const f16x8*)(Alds + ((size_t)(kk) << 9));                \
        const float* frow = fbuf[(kk) & 7][lh];                                \
        float fv0 = frow[w64 + l31], fv1 = frow[w64 + l31 + 32];               \
        f16 hR0 = (f16)fv0, hR1 = (f16)fv1;                                    \
        f16x2 fR0 = {hR0, hR0}, fR1 = {hR1, hR1};                              \
        f16x2 r0a = fR0 * s0a, r0b = fR0 * s0b, r0c = fR0 * s0c, r0d = fR0 * s0d; \
        f16x2 r1a = fR1 * s1a, r1b = fR1 * s1b, r1c = fR1 * s1c, r1d = fR1 * s1d; \
        f16x8 bS0 = {r0a[0],r0a[1],r0b[0],r0b[1],r0c[0],r0c[1],r0d[0],r0d[1]}; \
        f16x8 bS1 = {r1a[0],r1a[1],r1b[0],r1b[1],r1c[0],r1c[1],r1d[0],r1d[1]}; \
        acc0 = __builtin_amdgcn_mfma_f32_32x32x16_f16(aS, bS0, acc0, 0, 0, 0); \
        acc1 = __builtin_amdgcn_mfma_f32_32x32x16_f16(aS, bS1, acc1, 0, 0, 0); \
    }

#define PAIR(p)                                                                \
    STAGE(2 * (p) + 6) STAGE(2 * (p) + 7)                                      \
    WAITV(12);                                                                 \
    KSTEP(2 * (p)) KSTEP(2 * (p) + 1)

    PAIR(0)  PAIR(1)  PAIR(2)  PAIR(3)
    PAIR(4)  PAIR(5)  PAIR(6)  PAIR(7)
    PAIR(8)  PAIR(9)  PAIR(10) PAIR(11)
    PAIR(12)
    WAITV(8);
    KSTEP(26) KSTEP(27)
    WAITV(4);
    KSTEP(28) KSTEP(29)
    WAITV(0);
    KSTEP(30) KSTEP(31)
#undef PAIR
#undef KSTEP
#undef STAGE
#undef WAITV

    __builtin_amdgcn_sched_barrier(0);

    // ---- center correction: A = (-G) fragment from Gt (16 B/lane), B =
    // resident score regs half-zeroed; k-slot (lh*8+j) <-> (group lh, m=j).
    {
        const int g0 = (pblock + w64) >> 5;          // wave's first group
        const f16x8 a2 = *(const f16x8*)
            &Gt[((size_t)(g0 + lh) * 64 + ot * 32 + l31) * 8];
        f16x8 z8 = {};
        f16x8 bC0 = lh ? z8 : sv0;
        f16x8 bC1 = lh ? sv1 : z8;
        acc0 = __builtin_amdgcn_mfma_f32_32x32x16_f16(a2, bC0, acc0, 0, 0, 0);
        acc1 = __builtin_amdgcn_mfma_f32_32x32x16_f16(a2, bC1, acc1, 0, 0, 0);
    }

    // ---------------- epilogue: BN + ReLU + coalesced store ------------------
#pragma unroll
    for (int r = 0; r < 16; ++r) {
        int o = ot * 32 + (r & 3) + ((r >> 2) << 3) + (lh << 2);
        float gs = bn_g[o] * BNSCL, bb = bn_b[o];
        size_t row = (size_t)(b * 64 + o) << 15;
        out[row + pc0] = fmaxf(acc0[r] * gs + bb, 0.f);
        out[row + pc1] = fmaxf(acc1[r] * gs + bb, 0.f);
    }
}

// ---------------------------------------------------------------------------
extern "C" void kernel_launch(void* const* d_in, const int* in_sizes, int n_in,
                              void* d_out, int out_size, void* d_ws, size_t ws_size,
                              hipStream_t stream)
{
    const float* features = (const float*)d_in[0];
    const float* xyz      = (const float*)d_in[1];
    const float* w1  = (const float*)d_in[2];
    const float* g1  = (const float*)d_in[3];
    const float* be1 = (const float*)d_in[4];
    const float* w2  = (const float*)d_in[5];
    const float* g2  = (const float*)d_in[6];
    const float* be2 = (const float*)d_in[7];
    const float* w3  = (const float*)d_in[8];
    const float* g3  = (const float*)d_in[9];
    const float* be3 = (const float*)d_in[10];
    const float* w4  = (const float*)d_in[11];
    const float* b4  = (const float*)d_in[12];
    const float* wb  = (const float*)d_in[13];
    const float* bn_g = (const float*)d_in[14];
    const float* bn_b = (const float*)d_in[15];

    f16* scores = (f16*)d_ws;                                   // 4 MB
    f16* wbtA   = (f16*)((char*)d_ws + (4u << 20));             // 128 KB
    f16* Gt     = (f16*)((char*)d_ws + (4u << 20) + 131072);    // 8 MB

    k_pre<<<1280, 512, 0, stream>>>(xyz, w1, g1, be1, w2, g2, be2,
                                    w3, g3, be3, w4, b4, wb, wbtA,
                                    features, Gt, scores);
    k_main<<<512, 1024, 0, stream>>>(features, scores, wbtA, Gt,
                                     bn_g, bn_b, (float*)d_out);
}

// Round 11
// 188.410 us; speedup vs baseline: 1.0316x; 1.0011x over previous
//
#include <hip/hip_runtime.h>
#include <hip/hip_bf16.h>

typedef _Float16 f16;
typedef __attribute__((ext_vector_type(2))) _Float16 f16x2;
typedef __attribute__((ext_vector_type(8))) _Float16 f16x8;
typedef __attribute__((ext_vector_type(16))) float f32x16;

#define BNSCL 0.9999950000375f   /* 1/sqrt(1+1e-5) */

// ---------------------------------------------------------------------------
// Kernel 1 (ROUND 11): k_pre — fused pre-pass, 512-thr blocks, grid 384.
//   blocks 0..255 : scores MLP + softmax (2 pts/thread, scalar-K$ weights);
//                   blocks 0..127 also build wbtA (r8 layout, both banks).
//   blocks 256..383: G-GEMM, 128 blocks. r10 regression diagnosed: 1024
//                   G-blocks each re-gathered the D-bank (16K scalar loads)
//                   for only 8 jobs -> ~27 us. Now each block gathers ONCE
//                   and each wave runs 8 windows sequentially (64 jobs/block,
//                   8x amortization, 8x fewer blocks).
// ---------------------------------------------------------------------------
__global__ __launch_bounds__(512) void k_pre(
    const float* __restrict__ xyz,
    const float* __restrict__ w1, const float* __restrict__ g1, const float* __restrict__ be1,
    const float* __restrict__ w2, const float* __restrict__ g2, const float* __restrict__ be2,
    const float* __restrict__ w3, const float* __restrict__ g3, const float* __restrict__ be3,
    const float* __restrict__ w4, const float* __restrict__ b4,
    const float* __restrict__ wb, f16* __restrict__ wbtA,
    const float* __restrict__ feat, f16* __restrict__ Gt,
    f16* __restrict__ scores)
{
    __shared__ __align__(16) f16 ldsD[16384];   // 32 KB D-bank (G blocks only)
    __shared__ __align__(16) f16 gscr[8][512];  // 8 KB bounce (G blocks only)

    const int tid = threadIdx.x;
    const int bx  = blockIdx.x;

    if (bx >= 256) {
        // =================== G blocks (128) ===================
        const int gb   = bx - 256;              // 0..127
        const int ot   = gb >> 6;               // 0..1 (uniform per block)
        const int lane = tid & 63;
        const int wave = tid >> 6;              // 0..7
        const int l31  = lane & 31;
        const int lh   = lane >> 5;             // 0..1

        // ---- gather D bank from wb directly (once per block) ----
        // ldsD[(ks*64+lane)*8+j] = (f16)wb[(c*8+j)*64+o], c=ks*2+(lane>>5),
        // o=ot*32+(lane&31).
#pragma unroll
        for (int it = 0; it < 4; ++it) {
            int oct = it * 512 + tid;           // 0..2047 (octet index)
            int ln  = oct & 63;
            int ks  = oct >> 6;                 // 0..31
            int c   = ks * 2 + (ln >> 5);
            int o   = ot * 32 + (ln & 31);
            f16x8 v;
#pragma unroll
            for (int j = 0; j < 8; ++j) v[j] = (f16)wb[(c * 8 + j) * 64 + o];
            *(f16x8*)&ldsD[oct << 3] = v;
        }
        __syncthreads();

        // diagonal-mask pairs (r8/r9-proven)
        const bool mon  = (l31 < 16);
        const int  mpos = l31 & 7;
        const f16x2 mk0 = { (f16)((mon && mpos == 0) ? 1.f : 0.f),
                            (f16)((mon && mpos == 1) ? 1.f : 0.f) };
        const f16x2 mk1 = { (f16)((mon && mpos == 2) ? 1.f : 0.f),
                            (f16)((mon && mpos == 3) ? 1.f : 0.f) };
        const f16x2 mk2 = { (f16)((mon && mpos == 4) ? 1.f : 0.f),
                            (f16)((mon && mpos == 5) ? 1.f : 0.f) };
        const f16x2 mk3 = { (f16)((mon && mpos == 6) ? 1.f : 0.f),
                            (f16)((mon && mpos == 7) ? 1.f : 0.f) };

        const f16* Ad = ldsD + (lane << 3);

#pragma unroll 1
        for (int w = 0; w < 8; ++w) {           // 8 windows per wave, serial
            const int window = (gb & 63) * 64 + wave * 8 + w;   // 0..4095
            const int ptglob = window * 64;
            const int b      = ptglob >> 15;
            const int ptb    = ptglob & 32767;
            const float* fb  = feat + (size_t)b * 2097152;

            f32x16 accG = {};
#pragma unroll
            for (int kk = 0; kk < 32; ++kk) {
                f16x8 aD = *(const f16x8*)(Ad + ((size_t)kk << 9));
                const float* frow = fb + ((size_t)(2 * kk + lh) << 15) + ptb;
                float fcs = (l31 & 8) ? frow[32] : frow[0];
                f16 hC = (f16)(-fcs);
                f16x2 fg2 = {hC, hC};
                f16x2 q0 = mk0 * fg2, q1 = mk1 * fg2,
                      q2 = mk2 * fg2, q3 = mk3 * fg2;
                f16x8 bG = {q0[0],q0[1],q1[0],q1[1],q2[0],q2[1],q3[0],q3[1]};
                accG = __builtin_amdgcn_mfma_f32_32x32x16_f16(aD, bG, accG, 0, 0, 0);
            }

            // bounce accG (C/D: col=g*8+m for col<16; row o) -> [g][o][m]
            if (l31 < 16) {
                const int base = (l31 >> 3) * 256 + (l31 & 7);   // g*256 + m
#pragma unroll
                for (int r = 0; r < 16; ++r) {
                    int o = (r & 3) + ((r >> 2) << 3) + (lh << 2);
                    gscr[wave][base + o * 8] = (f16)accG[r];
                }
            }
            asm volatile("s_waitcnt lgkmcnt(0)" ::: "memory");
            __builtin_amdgcn_sched_barrier(0);
            {
                f16x8 gv = *(const f16x8*)&gscr[wave][lh * 256 + l31 * 8];
                size_t gg = (size_t)(window * 2 + lh);
                *(f16x8*)&Gt[(gg * 64 + ot * 32 + l31) * 8] = gv;
            }
            // drain the gv read before next window overwrites gscr
            asm volatile("s_waitcnt lgkmcnt(0)" ::: "memory");
        }
        return;
    }

    // =================== MLP / softmax blocks (0..255) ===================
    if (bx < 128) {
        int idx = bx * 512 + tid;               // 0..65535
        int j    = idx & 7;
        int lane = (idx >> 3) & 63;
        int ks   = (idx >> 9) & 31;
        int bank = (idx >> 14) & 1;             // 0 = S (combined), 1 = D
        int ot   = idx >> 15;
        int c    = ks * 2 + (lane >> 5);        // 0..63
        int o    = ot * 32 + (lane & 31);
        float vD = wb[(c * 8 + j) * 64 + o];
        float v  = bank ? vD : vD + wb[((c + 64) * 8 + j) * 64 + o];
        wbtA[idx] = (f16)v;
    }

    float in7[2][7], h1[2][16], h2[2][16], s[2][8];

#pragma unroll
    for (int q = 0; q < 2; ++q) {
        int g = bx * 1024 + q * 512 + tid;
        int b = g >> 15;
        int p = g & 32767;
        int pc = p & ~31;
        const float* xb = xyz + (size_t)b * 98304;
        float cx = xb[pc], cy = xb[32768 + pc], cz = xb[65536 + pc];
        float dx = xb[p] - cx, dy = xb[32768 + p] - cy, dz = xb[65536 + p] - cz;
        in7[q][0] = cx; in7[q][1] = cy; in7[q][2] = cz;
        in7[q][3] = dx; in7[q][4] = dy; in7[q][5] = dz;
        in7[q][6] = sqrtf(dx * dx + dy * dy + dz * dz);
    }

#pragma unroll
    for (int o = 0; o < 16; ++o) {
        float a0 = 0.f, a1 = 0.f;
#pragma unroll
        for (int c = 0; c < 7; ++c) {
            float w = w1[o * 7 + c];
            a0 += w * in7[0][c]; a1 += w * in7[1][c];
        }
        float gs = g1[o] * BNSCL, bb = be1[o];
        h1[0][o] = fmaxf(a0 * gs + bb, 0.f);
        h1[1][o] = fmaxf(a1 * gs + bb, 0.f);
    }
#pragma unroll
    for (int o = 0; o < 16; ++o) {
        float a0 = 0.f, a1 = 0.f;
#pragma unroll
        for (int c = 0; c < 16; ++c) {
            float w = w2[o * 16 + c];
            a0 += w * h1[0][c]; a1 += w * h1[1][c];
        }
        float gs = g2[o] * BNSCL, bb = be2[o];
        h2[0][o] = fmaxf(a0 * gs + bb, 0.f);
        h2[1][o] = fmaxf(a1 * gs + bb, 0.f);
    }
#pragma unroll
    for (int o = 0; o < 16; ++o) {
        float a0 = 0.f, a1 = 0.f;
#pragma unroll
        for (int c = 0; c < 16; ++c) {
            float w = w3[o * 16 + c];
            a0 += w * h2[0][c]; a1 += w * h2[1][c];
        }
        float gs = g3[o] * BNSCL, bb = be3[o];
        h1[0][o] = fmaxf(a0 * gs + bb, 0.f);
        h1[1][o] = fmaxf(a1 * gs + bb, 0.f);
    }
#pragma unroll
    for (int o = 0; o < 8; ++o) {
        float bb = b4[o];
        float a0 = bb, a1 = bb;
#pragma unroll
        for (int c = 0; c < 16; ++c) {
            float w = w4[o * 16 + c];
            a0 += w * h1[0][c]; a1 += w * h1[1][c];
        }
        s[0][o] = a0; s[1][o] = a1;
    }

#pragma unroll
    for (int q = 0; q < 2; ++q) {
        int g = bx * 1024 + q * 512 + tid;
        float mx = s[q][0];
#pragma unroll
        for (int i = 1; i < 8; ++i) mx = fmaxf(mx, s[q][i]);
        float sum = 0.f;
#pragma unroll
        for (int i = 0; i < 8; ++i) { s[q][i] = __expf(s[q][i] - mx); sum += s[q][i]; }
        float inv = 1.f / sum;
        f16x8 o8;
#pragma unroll
        for (int i = 0; i < 8; ++i) o8[i] = (f16)(s[q][i] * inv);
        *(f16x8*)(scores + (size_t)g * 8) = o8;
    }
}

// ---------------------------------------------------------------------------
// Kernel 2 (ROUND 11): main einsum — BOTH o-tile halves per block.
// The B-fragments (fv x scores) are identical for both ot halves; r10
// computed them twice in separate blocks. Fused: grid 256 (1 block/CU),
// LDS = 64 KB (both S banks) + 64 KB fbuf = 128 KB; 4 accumulators.
// Per KSTEP: 2 ds_read_b128 + 2 ds_read_b32 + 8 muls + 4 MFMA — per point,
// b32 reads, VALU muls, feat DMA, and score loads are HALVED vs r10.
// Schedule = r6 distance-6 DMA pipeline unchanged.
// ---------------------------------------------------------------------------
__global__ __launch_bounds__(1024, 4) void k_main(
    const float* __restrict__ feat,
    const f16* __restrict__ scores,
    const f16* __restrict__ wbtA,
    const f16* __restrict__ Gt,
    const float* __restrict__ bn_g, const float* __restrict__ bn_b,
    float* __restrict__ out)
{
    __shared__ __align__(16) f16 lwb[32768];         // 64 KB: S ot0 | S ot1
    __shared__ __align__(16) float fbuf[8][2][1024]; // 64 KB feat 8-slot buf

    const int tid  = threadIdx.x;
    const int lane = tid & 63;
    const int wave = tid >> 6;          // 0..15
    const int l31  = lane & 31;
    const int lh   = lane >> 5;         // 0..1
    const int w64  = wave * 64;

    const int g  = blockIdx.x;                  // 0..255 point-group
    const int pblock = g * 1024;                // global point base
    const int b    = pblock >> 15;
    const int pt0  = (pblock & 32767) + w64;    // within-batch, 32-aligned
    const int pc0  = pt0 + l31;
    const int pc1  = pc0 + 32;

    const float* fb = feat + (size_t)b * 2097152;    // (64, 32768)
    const float* gsrc0 = fb + (pblock & 32767) + w64 + lane;

    // ---- stage BOTH S-banks into LDS (wbtA: ot0 S at 0, ot1 S at 32768) ----
#pragma unroll
    for (int it = 0; it < 2; ++it) {
        int idx = it * 1024 + tid;                   // 0..2047 16B-chunks
        *(int4*)&lwb[idx << 3] = *(const int4*)&wbtA[idx << 3];
        *(int4*)&lwb[16384 + (idx << 3)] = *(const int4*)&wbtA[32768 + (idx << 3)];
    }

    // ---- scores: load + extract to registers ----
    const int gpt = pblock + w64 + l31;
    f16x8 sv0 = *(const f16x8*)(scores + (size_t)gpt * 8);
    f16x8 sv1 = *(const f16x8*)(scores + (size_t)(gpt + 32) * 8);
    const f16x2 s0a = {sv0[0], sv0[1]}, s0b = {sv0[2], sv0[3]},
                s0c = {sv0[4], sv0[5]}, s0d = {sv0[6], sv0[7]};
    const f16x2 s1a = {sv1[0], sv1[1]}, s1b = {sv1[2], sv1[3]},
                s1c = {sv1[4], sv1[5]}, s1d = {sv1[6], sv1[7]};

    f32x16 accA0 = {}, accA1 = {};   // ot = 0
    f32x16 accB0 = {}, accB1 = {};   // ot = 1
    const f16* Alds = lwb + (lane << 3);             // lane's 16B slot

#define STAGE(t)                                                               \
    {                                                                          \
        __builtin_amdgcn_global_load_lds(                                      \
            (const __attribute__((address_space(1))) void*)                    \
                (gsrc0 + ((size_t)(2 * (t)) << 15)),                           \
            (__attribute__((address_space(3))) void*)&fbuf[(t) & 7][0][w64],   \
            4, 0, 0);                                                          \
        __builtin_amdgcn_global_load_lds(                                      \
            (const __attribute__((address_space(1))) void*)                    \
                (gsrc0 + ((size_t)(2 * (t) + 1) << 15)),                       \
            (__attribute__((address_space(3))) void*)&fbuf[(t) & 7][1][w64],   \
            4, 0, 0);                                                          \
    }

#define WAITV(n) asm volatile("s_waitcnt vmcnt(" #n ")" ::: "memory")

    __builtin_amdgcn_sched_barrier(0);
    STAGE(0); STAGE(1); STAGE(2); STAGE(3); STAGE(4); STAGE(5);

    asm volatile("s_waitcnt lgkmcnt(0)" ::: "memory");
    __builtin_amdgcn_s_barrier();

#define KSTEP(kk)                                                              \
    {                                                                          \
        f16x8 aS0 = *(const f16x8*)(Alds + ((size_t)(kk) << 9));               \
        f16x8 aS1 = *(const f16x8*)(Alds + 16384 + ((size_t)(kk) << 9));       \
        const float* frow = fbuf[(kk) & 7][lh];                                \
        float fv0 = frow[w64 + l31], fv1 = frow[w64 + l31 + 32];               \
        f16 hR0 = (f16)fv0, hR1 = (f16)fv1;                                    \
        f16x2 fR0 = {hR0, hR0}, fR1 = {hR1, hR1};                              \
        f16x2 r0a = fR0 * s0a, r0b = fR0 * s0b, r0c = fR0 * s0c, r0d = fR0 * s0d; \
        f16x2 r1a = fR1 * s1a, r1b = fR1 * s1b, r1c = fR1 * s1c, r1d = fR1 * s1d; \
        f16x8 bS0 = {r0a[0],r0a[1],r0b[0],r0b[1],r0c[0],r0c[1],r0d[0],r0d[1]}; \
        f16x8 bS1 = {r1a[0],r1a[1],r1b[0],r1b[1],r1c[0],r1c[1],r1d[0],r1d[1]}; \
        accA0 = __builtin_amdgcn_mfma_f32_32x32x16_f16(aS0, bS0, accA0, 0, 0, 0); \
        accA1 = __builtin_amdgcn_mfma_f32_32x32x16_f16(aS0, bS1, accA1, 0, 0, 0); \
        accB0 = __builtin_amdgcn_mfma_f32_32x32x16_f16(aS1, bS0, accB0, 0, 0, 0); \
        accB1 = __builtin_amdgcn_mfma_f32_32x32x16_f16(aS1, bS1, accB1, 0, 0, 0); \
    }

#define PAIR(p)                                                                \
    STAGE(2 * (p) + 6) STAGE(2 * (p) + 7)                                      \
    WAITV(12);                                                                 \
    KSTEP(2 * (p)) KSTEP(2 * (p) + 1)

    PAIR(0)  PAIR(1)  PAIR(2)  PAIR(3)
    PAIR(4)  PAIR(5)  PAIR(6)  PAIR(7)
    PAIR(8)  PAIR(9)  PAIR(10) PAIR(11)
    PAIR(12)
    WAITV(8);
    KSTEP(26) KSTEP(27)
    WAITV(4);
    KSTEP(28) KSTEP(29)
    WAITV(0);
    KSTEP(30) KSTEP(31)
#undef PAIR
#undef KSTEP
#undef STAGE
#undef WAITV

    __builtin_amdgcn_sched_barrier(0);

    // ---- center correction: A = (-G) fragments from Gt (16 B/lane per ot),
    // B = resident score regs half-zeroed; k-slot (lh*8+j) <-> (group lh, m=j).
    {
        const int g0 = (pblock + w64) >> 5;          // wave's first group
        const f16* gtb = Gt + ((size_t)(g0 + lh) * 64 + l31) * 8;
        const f16x8 a2_0 = *(const f16x8*)gtb;               // ot0 (o = l31)
        const f16x8 a2_1 = *(const f16x8*)(gtb + 256);       // ot1 (o = 32+l31)
        f16x8 z8 = {};
        f16x8 bC0 = lh ? z8 : sv0;
        f16x8 bC1 = lh ? sv1 : z8;
        accA0 = __builtin_amdgcn_mfma_f32_32x32x16_f16(a2_0, bC0, accA0, 0, 0, 0);
        accA1 = __builtin_amdgcn_mfma_f32_32x32x16_f16(a2_0, bC1, accA1, 0, 0, 0);
        accB0 = __builtin_amdgcn_mfma_f32_32x32x16_f16(a2_1, bC0, accB0, 0, 0, 0);
        accB1 = __builtin_amdgcn_mfma_f32_32x32x16_f16(a2_1, bC1, accB1, 0, 0, 0);
    }

    // ---------------- epilogue: BN + ReLU + coalesced store ------------------
    // C layout: col = lane&31, row = (r&3) + 8*(r>>2) + 4*lh
#pragma unroll
    for (int r = 0; r < 16; ++r) {
        int oo = (r & 3) + ((r >> 2) << 3) + (lh << 2);
        // ot = 0
        {
            float gs = bn_g[oo] * BNSCL, bb = bn_b[oo];
            size_t row = (size_t)(b * 64 + oo) << 15;
            out[row + pc0] = fmaxf(accA0[r] * gs + bb, 0.f);
            out[row + pc1] = fmaxf(accA1[r] * gs + bb, 0.f);
        }
        // ot = 1
        {
            int o1 = 32 + oo;
            float gs = bn_g[o1] * BNSCL, bb = bn_b[o1];
            size_t row = (size_t)(b * 64 + o1) << 15;
            out[row + pc0] = fmaxf(accB0[r] * gs + bb, 0.f);
            out[row + pc1] = fmaxf(accB1[r] * gs + bb, 0.f);
        }
    }
}

// ---------------------------------------------------------------------------
extern "C" void kernel_launch(void* const* d_in, const int* in_sizes, int n_in,
                              void* d_out, int out_size, void* d_ws, size_t ws_size,
                              hipStream_t stream)
{
    const float* features = (const float*)d_in[0];
    const float* xyz      = (const float*)d_in[1];
    const float* w1  = (const float*)d_in[2];
    const float* g1  = (const float*)d_in[3];
    const float* be1 = (const float*)d_in[4];
    const float* w2  = (const float*)d_in[5];
    const float* g2  = (const float*)d_in[6];
    const float* be2 = (const float*)d_in[7];
    const float* w3  = (const float*)d_in[8];
    const float* g3  = (const float*)d_in[9];
    const float* be3 = (const float*)d_in[10];
    const float* w4  = (const float*)d_in[11];
    const float* b4  = (const float*)d_in[12];
    const float* wb  = (const float*)d_in[13];
    const float* bn_g = (const float*)d_in[14];
    const float* bn_b = (const float*)d_in[15];

    f16* scores = (f16*)d_ws;                                   // 4 MB
    f16* wbtA   = (f16*)((char*)d_ws + (4u << 20));             // 128 KB
    f16* Gt     = (f16*)((char*)d_ws + (4u << 20) + 131072);    // 8 MB

    k_pre<<<384, 512, 0, stream>>>(xyz, w1, g1, be1, w2, g2, be2,
                                   w3, g3, be3, w4, b4, wb, wbtA,
                                   features, Gt, scores);
    k_main<<<256, 1024, 0, stream>>>(features, scores, wbtA, Gt,
                                     bn_g, bn_b, (float*)d_out);
}